// Round 8
// baseline (223.276 us; speedup 1.0000x reference)
//
#include <hip/hip_runtime.h>

typedef unsigned short u16;
typedef float f32x4 __attribute__((ext_vector_type(4)));
typedef short bf16x8 __attribute__((ext_vector_type(8)));
typedef u16 u16x4 __attribute__((ext_vector_type(4)));
typedef u16 u16x8 __attribute__((ext_vector_type(8)));
typedef __bf16 bfr4 __attribute__((ext_vector_type(4)));

// ---- constants ----
#define BB 2
#define NN 2048
#define CC 1024
#define HH 16
#define DD 64
#define MM (BB * NN)          // 4096 rows
#define NQKV (3 * CC)         // 3072
#define QSCALE 0.18033688011112042f   // 0.125 * log2(e): scores in log2 domain

#if __has_builtin(__builtin_amdgcn_exp2f)
#define EXP2(x) __builtin_amdgcn_exp2f(x)
#else
#define EXP2(x) exp2f(x)
#endif

__device__ __forceinline__ u16 f2bf(float f) {
    unsigned u = __float_as_uint(f);
    u += 0x7FFFu + ((u >> 16) & 1u);   // round-to-nearest-even
    return (u16)(u >> 16);
}
__device__ __forceinline__ float bf2f(u16 b) {
    return __uint_as_float(((unsigned)b) << 16);
}

// async global->LDS, 16B per lane. LDS dst must be wave-uniform base + lane*16.
__device__ __forceinline__ void ld_lds16(const u16* g, u16* l) {
    __builtin_amdgcn_global_load_lds(
        (const __attribute__((address_space(1))) unsigned int*)g,
        (__attribute__((address_space(3))) unsigned int*)l, 16, 0, 0);
}

// ---- fp32 -> bf16 cast (x) ----
__global__ __launch_bounds__(256) void k_tobf(const float* __restrict__ in,
                                              u16* __restrict__ out, int n) {
    int i = (blockIdx.x * 256 + threadIdx.x) * 8;
    if (i >= n) return;
    float4 a = *(const float4*)(in + i);
    float4 b = *(const float4*)(in + i + 4);
    u16x8 o;
    o[0] = f2bf(a.x); o[1] = f2bf(a.y); o[2] = f2bf(a.z); o[3] = f2bf(a.w);
    o[4] = f2bf(b.x); o[5] = f2bf(b.y); o[6] = f2bf(b.z); o[7] = f2bf(b.w);
    *(u16x8*)(out + i) = o;
}

// ---- transpose-cast [K][Nn] fp32 -> [Nn][K] bf16 (weights) ----
__global__ __launch_bounds__(256) void k_tcast(const float* __restrict__ in,
                                               u16* __restrict__ out,
                                               int K, int Nn) {
    __shared__ float tile[32][33];
    int t = threadIdx.x, tx = t & 31, ty = t >> 5;
    int n0 = blockIdx.x * 32, k0 = blockIdx.y * 32;
#pragma unroll
    for (int r = 0; r < 32; r += 8)
        tile[ty + r][tx] = in[(size_t)(k0 + ty + r) * Nn + n0 + tx];
    __syncthreads();
#pragma unroll
    for (int r = 0; r < 32; r += 8)
        out[(size_t)(n0 + ty + r) * K + k0 + tx] = f2bf(tile[tx][ty + r]);
}

// ---- plain bf16 GEMM C = A @ B^T, K=1024, BK=32 (round-5 config) ----
template <int MODE>
__global__ __launch_bounds__(256) void k_gemm(
    const u16* __restrict__ A, const u16* __restrict__ B,
    u16* __restrict__ Qb, u16* __restrict__ Kb, u16* __restrict__ Vb,
    const float* __restrict__ bias, float* __restrict__ Cout) {
    const int Kd = 1024;
    __shared__ __align__(16) u16 Ah[128][32];
    __shared__ __align__(16) u16 Bh[128][32];

    int t = threadIdx.x;
    int wave = t >> 6, lane = t & 63;
    int quad = lane >> 4, l16 = lane & 15;
    int wm = (wave >> 1) * 64, wn = (wave & 1) * 64;
    int m0 = blockIdx.y * 128, n0 = blockIdx.x * 128;

    int strow0 = wave * 16 + (lane >> 2);              // + ii*64
    int stdst  = (lane & 3) * 8;                       // lds col (u16)
    int stsrc  = ((lane & 3) ^ ((lane >> 3) & 3)) * 8; // global col (u16)
    int cfrag = (quad ^ ((l16 >> 1) & 3)) * 8;

    f32x4 acc[4][4];
#pragma unroll
    for (int i = 0; i < 4; i++)
#pragma unroll
        for (int j = 0; j < 4; j++) acc[i][j] = f32x4{0.f, 0.f, 0.f, 0.f};

    for (int k0 = 0; k0 < Kd; k0 += 32) {
        __syncthreads();
#pragma unroll
        for (int ii = 0; ii < 2; ii++) {
            int row = strow0 + ii * 64;
            ld_lds16(A + (size_t)(m0 + row) * Kd + k0 + stsrc, &Ah[row][stdst]);
            ld_lds16(B + (size_t)(n0 + row) * Kd + k0 + stsrc, &Bh[row][stdst]);
        }
        __syncthreads();

        bf16x8 af[4], bf[4];
#pragma unroll
        for (int i = 0; i < 4; i++) {
            af[i] = *(const bf16x8*)&Ah[wm + i * 16 + l16][cfrag];
            bf[i] = *(const bf16x8*)&Bh[wn + i * 16 + l16][cfrag];
        }
#pragma unroll
        for (int mi = 0; mi < 4; mi++)
#pragma unroll
            for (int ni = 0; ni < 4; ni++)
                acc[mi][ni] = __builtin_amdgcn_mfma_f32_16x16x32_bf16(
                    af[mi], bf[ni], acc[mi][ni], 0, 0, 0);
    }

#pragma unroll
    for (int mi = 0; mi < 4; mi++)
#pragma unroll
        for (int ni = 0; ni < 4; ni++)
#pragma unroll
            for (int r = 0; r < 4; r++) {
                int grow = m0 + wm + mi * 16 + quad * 4 + r;
                int gcol = n0 + wn + ni * 16 + l16;
                float v = acc[mi][ni][r];
                if (MODE == 0) {
                    int three = gcol >> 10, rem = gcol & 1023;
                    int h = rem >> 6, d = rem & 63;
                    int bb = grow >> 11, nn = grow & 2047;
                    if (three == 0) {
                        Qb[((size_t)(bb * HH + h) * NN + nn) * DD + d] = f2bf(v * QSCALE);
                    } else if (three == 1) {
                        Kb[((size_t)(bb * HH + h) * NN + nn) * DD + d] = f2bf(v);
                    } else {
                        Vb[((size_t)(bb * HH + h) * DD + d) * NN + nn] = f2bf(v);
                    }
                } else {
                    Cout[(size_t)grow * CC + gcol] = v + bias[gcol];
                }
            }
}

// ---- flash attention: 4-wave blocks, 256 q/block (64 q/wave), key-split x2 ----
// Q,K: [BH][N][D] bf16 (Q pre-scaled by 0.125*log2e); V^T: [BH][D][N]
// writes UNNORMALIZED partials: Opart bf16 [2][M][C], Lpart f32 [2][M][HH]
__global__ __launch_bounds__(256) void k_attn(const u16* __restrict__ Qb,
                                              const u16* __restrict__ Kb,
                                              const u16* __restrict__ VbT,
                                              u16* __restrict__ Opart,
                                              float* __restrict__ Lpart) {
    __shared__ __align__(16) u16 Ks[64][64];      // swizzled, 8KB
    __shared__ __align__(16) u16 Vs[64][64];      // 8KB
    __shared__ __align__(16) u16 Ps[4][64][64];   // per-wave 64q P^T, 32KB

    int t = threadIdx.x, wave = t >> 6, lane = t & 63;
    int quad = lane >> 4, l16 = lane & 15;
    int bh = blockIdx.y, sp = blockIdx.z;
    int q0 = blockIdx.x * 256 + wave * 64;        // this wave's 64 q
    const size_t kbase = (size_t)bh * NN * DD;
    const size_t vbase = (size_t)bh * DD * NN;

    bf16x8 qf[4][2];
#pragma unroll
    for (int qj = 0; qj < 4; qj++) {
        int qrow = q0 + qj * 16 + l16;
        qf[qj][0] = *(const bf16x8*)&Qb[kbase + (size_t)qrow * DD + quad * 8];
        qf[qj][1] = *(const bf16x8*)&Qb[kbase + (size_t)qrow * DD + 32 + quad * 8];
    }

    bf16x8 ones;
#pragma unroll
    for (int j = 0; j < 8; j++) ones[j] = (short)0x3F80;   // bf16 1.0

    f32x4 o[4][4];    // [dt][qj]: O^T rows d = dt*16+quad*4+r, col q = l16
    f32x4 accl[4];    // [qj]: all entries = l[q=l16]
#pragma unroll
    for (int i = 0; i < 4; i++) {
        accl[i] = f32x4{0.f, 0.f, 0.f, 0.f};
#pragma unroll
        for (int j = 0; j < 4; j++) o[i][j] = f32x4{0.f, 0.f, 0.f, 0.f};
    }

    int stgrp  = lane & 7;
    int stsrc  = (stgrp ^ (lane >> 3)) * 8;
    int strow0 = wave * 16 + (lane >> 3);         // + ii*8, ii=0..1 (16 rows/wave)
    int cf0 = (quad ^ (l16 & 7)) * 8;
    int cf1 = ((4 + quad) ^ (l16 & 7)) * 8;
    int psw = (quad & 1) * 4;

    for (int c = sp * 16; c < sp * 16 + 16; c++) {
        __syncthreads();
#pragma unroll
        for (int ii = 0; ii < 2; ii++) {
            int row = strow0 + ii * 8;
            ld_lds16(&Kb[kbase + (size_t)(c * 64 + row) * DD + stsrc], &Ks[row][stgrp * 8]);
            ld_lds16(&VbT[vbase + (size_t)row * NN + c * 64 + stsrc], &Vs[row][stgrp * 8]);
        }
        __syncthreads();

        // K-frags hoisted once, reused across 4 qj
        bf16x8 kf[4][2];
#pragma unroll
        for (int kt = 0; kt < 4; kt++) {
            kf[kt][0] = *(const bf16x8*)&Ks[kt * 16 + l16][cf0];
            kf[kt][1] = *(const bf16x8*)&Ks[kt * 16 + l16][cf1];
        }

#pragma unroll
        for (int qj = 0; qj < 4; qj++) {
            f32x4 s[4];
#pragma unroll
            for (int kt = 0; kt < 4; kt++) {
                f32x4 z = f32x4{0.f, 0.f, 0.f, 0.f};
                z = __builtin_amdgcn_mfma_f32_16x16x32_bf16(kf[kt][0], qf[qj][0], z, 0, 0, 0);
                z = __builtin_amdgcn_mfma_f32_16x16x32_bf16(kf[kt][1], qf[qj][1], z, 0, 0, 0);
                s[kt] = z;   // rows k = kt*16+quad*4+r, col q = l16
            }
#pragma unroll
            for (int kt = 0; kt < 4; kt++) {
                bfr4 pk;
#pragma unroll
                for (int r = 0; r < 4; r++) pk[r] = (__bf16)EXP2(s[kt][r]);
                int og = 2 * kt + (quad >> 1);
                *(bfr4*)&Ps[wave][qj * 16 + l16][(og ^ (l16 & 7)) * 8 + psw] = pk;
            }
        }
        // wave-local DS write->read ordering
        __asm__ volatile("s_waitcnt lgkmcnt(0)" ::: "memory");

        bf16x8 pb[4][2];
#pragma unroll
        for (int qj = 0; qj < 4; qj++) {
            pb[qj][0] = *(const bf16x8*)&Ps[wave][qj * 16 + l16][cf0];
            pb[qj][1] = *(const bf16x8*)&Ps[wave][qj * 16 + l16][cf1];
            accl[qj] = __builtin_amdgcn_mfma_f32_16x16x32_bf16(ones, pb[qj][0], accl[qj], 0, 0, 0);
            accl[qj] = __builtin_amdgcn_mfma_f32_16x16x32_bf16(ones, pb[qj][1], accl[qj], 0, 0, 0);
        }
#pragma unroll
        for (int dt = 0; dt < 4; dt++) {
            bf16x8 vf0 = *(const bf16x8*)&Vs[dt * 16 + l16][cf0];
            bf16x8 vf1 = *(const bf16x8*)&Vs[dt * 16 + l16][cf1];
#pragma unroll
            for (int qj = 0; qj < 4; qj++) {
                o[dt][qj] = __builtin_amdgcn_mfma_f32_16x16x32_bf16(vf0, pb[qj][0], o[dt][qj], 0, 0, 0);
                o[dt][qj] = __builtin_amdgcn_mfma_f32_16x16x32_bf16(vf1, pb[qj][1], o[dt][qj], 0, 0, 0);
            }
        }
    }

    // epilogue: write unnormalized bf16 partials + f32 l-partials
    int b = bh >> 4, h = bh & 15;
#pragma unroll
    for (int qj = 0; qj < 4; qj++) {
        int grow = b * NN + q0 + qj * 16 + l16;
        size_t orow = ((size_t)sp * MM + grow) * CC;
#pragma unroll
        for (int dt = 0; dt < 4; dt++) {
            u16x4 hv;
#pragma unroll
            for (int r = 0; r < 4; r++) hv[r] = f2bf(o[dt][qj][r]);
            *(u16x4*)&Opart[orow + h * DD + dt * 16 + quad * 4] = hv;
        }
        if (quad == 0)
            Lpart[((size_t)sp * MM + grow) * HH + h] = accl[qj][0];
    }
}

// ---- combine key-split partials, normalize, write bf16 Ob [M][C] ----
__global__ __launch_bounds__(256) void k_reduce(const u16* __restrict__ Op,
                                                const float* __restrict__ Lp,
                                                u16* __restrict__ Ob) {
    size_t i = ((size_t)blockIdx.x * 256 + threadIdx.x) * 8;
    int m = (int)(i >> 10);          // / CC
    int c = (int)(i & 1023);
    int h = c >> 6;
    float l = Lp[(size_t)m * HH + h] + Lp[(size_t)(MM + m) * HH + h];
    float inv = 1.f / l;
    u16x8 p0 = *(const u16x8*)&Op[i];
    u16x8 p1 = *(const u16x8*)&Op[(size_t)MM * CC + i];
    u16x8 o;
#pragma unroll
    for (int j = 0; j < 8; j++) o[j] = f2bf((bf2f(p0[j]) + bf2f(p1[j])) * inv);
    *(u16x8*)&Ob[i] = o;
}

extern "C" void kernel_launch(void* const* d_in, const int* in_sizes, int n_in,
                              void* d_out, int out_size, void* d_ws, size_t ws_size,
                              hipStream_t stream) {
    const float* x      = (const float*)d_in[0];
    const float* w_qkv  = (const float*)d_in[1];
    const float* w_proj = (const float*)d_in[2];
    const float* b_proj = (const float*)d_in[3];
    float* out = (float*)d_out;

    u16* p = (u16*)d_ws;
    u16* Xb = p; p += (size_t)MM * CC;
    u16* Wq = p; p += (size_t)NQKV * CC;
    u16* Wp = p; p += (size_t)CC * CC;
    u16* Qb = p; p += (size_t)MM * CC;
    u16* Kb = p; p += (size_t)MM * CC;
    u16* Vb = p; p += (size_t)MM * CC;           // V^T [BH][D][N]
    u16* Ob = p; p += (size_t)MM * CC;
    u16* Opart = p; p += (size_t)2 * MM * CC;    // bf16 partials [2][M][C]
    float* Lpart = (float*)p;                    // f32 [2][M][HH]

    k_tobf<<<(MM * CC) / (256 * 8), 256, 0, stream>>>(x, Xb, MM * CC);
    k_tcast<<<dim3(NQKV / 32, CC / 32), 256, 0, stream>>>(w_qkv, Wq, CC, NQKV);
    k_tcast<<<dim3(CC / 32, CC / 32), 256, 0, stream>>>(w_proj, Wp, CC, CC);
    k_gemm<0><<<dim3(NQKV / 128, MM / 128), 256, 0, stream>>>(
        Xb, Wq, Qb, Kb, Vb, nullptr, nullptr);
    k_attn<<<dim3(NN / 256, BB * HH, 2), 256, 0, stream>>>(Qb, Kb, Vb, Opart, Lpart);
    k_reduce<<<(MM * CC) / (256 * 8), 256, 0, stream>>>(Opart, Lpart, Ob);
    k_gemm<1><<<dim3(CC / 128, MM / 128), 256, 0, stream>>>(
        Ob, Wp, nullptr, nullptr, nullptr, b_proj, out);
}

// Round 9
// 208.862 us; speedup vs baseline: 1.0690x; 1.0690x over previous
//
#include <hip/hip_runtime.h>

typedef unsigned short u16;
typedef float f32x4 __attribute__((ext_vector_type(4)));
typedef short bf16x8 __attribute__((ext_vector_type(8)));
typedef u16 u16x4 __attribute__((ext_vector_type(4)));
typedef u16 u16x8 __attribute__((ext_vector_type(8)));
typedef __bf16 bfr4 __attribute__((ext_vector_type(4)));

// ---- constants ----
#define BB 2
#define NN 2048
#define CC 1024
#define HH 16
#define DD 64
#define MM (BB * NN)          // 4096 rows
#define NQKV (3 * CC)         // 3072
#define QSCALE 0.18033688011112042f   // 0.125 * log2(e): scores in log2 domain

#if __has_builtin(__builtin_amdgcn_exp2f)
#define EXP2(x) __builtin_amdgcn_exp2f(x)
#else
#define EXP2(x) exp2f(x)
#endif

__device__ __forceinline__ u16 f2bf(float f) {
    unsigned u = __float_as_uint(f);
    u += 0x7FFFu + ((u >> 16) & 1u);   // round-to-nearest-even
    return (u16)(u >> 16);
}
__device__ __forceinline__ float bf2f(u16 b) {
    return __uint_as_float(((unsigned)b) << 16);
}

// async global->LDS, 16B per lane. LDS dst must be wave-uniform base + lane*16.
__device__ __forceinline__ void ld_lds16(const u16* g, u16* l) {
    __builtin_amdgcn_global_load_lds(
        (const __attribute__((address_space(1))) unsigned int*)g,
        (__attribute__((address_space(3))) unsigned int*)l, 16, 0, 0);
}

// ---- fp32 -> bf16 cast (x) ----
__global__ __launch_bounds__(256) void k_tobf(const float* __restrict__ in,
                                              u16* __restrict__ out, int n) {
    int i = (blockIdx.x * 256 + threadIdx.x) * 8;
    if (i >= n) return;
    float4 a = *(const float4*)(in + i);
    float4 b = *(const float4*)(in + i + 4);
    u16x8 o;
    o[0] = f2bf(a.x); o[1] = f2bf(a.y); o[2] = f2bf(a.z); o[3] = f2bf(a.w);
    o[4] = f2bf(b.x); o[5] = f2bf(b.y); o[6] = f2bf(b.z); o[7] = f2bf(b.w);
    *(u16x8*)(out + i) = o;
}

// ---- transpose-cast [K][Nn] fp32 -> [Nn][K] bf16 (weights) ----
__global__ __launch_bounds__(256) void k_tcast(const float* __restrict__ in,
                                               u16* __restrict__ out,
                                               int K, int Nn) {
    __shared__ float tile[32][33];
    int t = threadIdx.x, tx = t & 31, ty = t >> 5;
    int n0 = blockIdx.x * 32, k0 = blockIdx.y * 32;
#pragma unroll
    for (int r = 0; r < 32; r += 8)
        tile[ty + r][tx] = in[(size_t)(k0 + ty + r) * Nn + n0 + tx];
    __syncthreads();
#pragma unroll
    for (int r = 0; r < 32; r += 8)
        out[(size_t)(n0 + ty + r) * K + k0 + tx] = f2bf(tile[tx][ty + r]);
}

// ---- plain bf16 GEMM C = A @ B^T, K=1024, BK=32 (round-5 config) ----
template <int MODE>
__global__ __launch_bounds__(256) void k_gemm(
    const u16* __restrict__ A, const u16* __restrict__ B,
    u16* __restrict__ Qb, u16* __restrict__ Kb, u16* __restrict__ Vb,
    const float* __restrict__ bias, float* __restrict__ Cout) {
    const int Kd = 1024;
    __shared__ __align__(16) u16 Ah[128][32];
    __shared__ __align__(16) u16 Bh[128][32];

    int t = threadIdx.x;
    int wave = t >> 6, lane = t & 63;
    int quad = lane >> 4, l16 = lane & 15;
    int wm = (wave >> 1) * 64, wn = (wave & 1) * 64;
    int m0 = blockIdx.y * 128, n0 = blockIdx.x * 128;

    int strow0 = wave * 16 + (lane >> 2);              // + ii*64
    int stdst  = (lane & 3) * 8;                       // lds col (u16)
    int stsrc  = ((lane & 3) ^ ((lane >> 3) & 3)) * 8; // global col (u16)
    int cfrag = (quad ^ ((l16 >> 1) & 3)) * 8;

    f32x4 acc[4][4];
#pragma unroll
    for (int i = 0; i < 4; i++)
#pragma unroll
        for (int j = 0; j < 4; j++) acc[i][j] = f32x4{0.f, 0.f, 0.f, 0.f};

    for (int k0 = 0; k0 < Kd; k0 += 32) {
        __syncthreads();
#pragma unroll
        for (int ii = 0; ii < 2; ii++) {
            int row = strow0 + ii * 64;
            ld_lds16(A + (size_t)(m0 + row) * Kd + k0 + stsrc, &Ah[row][stdst]);
            ld_lds16(B + (size_t)(n0 + row) * Kd + k0 + stsrc, &Bh[row][stdst]);
        }
        __syncthreads();

        bf16x8 af[4], bf[4];
#pragma unroll
        for (int i = 0; i < 4; i++) {
            af[i] = *(const bf16x8*)&Ah[wm + i * 16 + l16][cfrag];
            bf[i] = *(const bf16x8*)&Bh[wn + i * 16 + l16][cfrag];
        }
#pragma unroll
        for (int mi = 0; mi < 4; mi++)
#pragma unroll
            for (int ni = 0; ni < 4; ni++)
                acc[mi][ni] = __builtin_amdgcn_mfma_f32_16x16x32_bf16(
                    af[mi], bf[ni], acc[mi][ni], 0, 0, 0);
    }

#pragma unroll
    for (int mi = 0; mi < 4; mi++)
#pragma unroll
        for (int ni = 0; ni < 4; ni++)
#pragma unroll
            for (int r = 0; r < 4; r++) {
                int grow = m0 + wm + mi * 16 + quad * 4 + r;
                int gcol = n0 + wn + ni * 16 + l16;
                float v = acc[mi][ni][r];
                if (MODE == 0) {
                    int three = gcol >> 10, rem = gcol & 1023;
                    int h = rem >> 6, d = rem & 63;
                    int bb = grow >> 11, nn = grow & 2047;
                    if (three == 0) {
                        Qb[((size_t)(bb * HH + h) * NN + nn) * DD + d] = f2bf(v * QSCALE);
                    } else if (three == 1) {
                        Kb[((size_t)(bb * HH + h) * NN + nn) * DD + d] = f2bf(v);
                    } else {
                        Vb[((size_t)(bb * HH + h) * DD + d) * NN + nn] = f2bf(v);
                    }
                } else {
                    Cout[(size_t)grow * CC + gcol] = v + bias[gcol];
                }
            }
}

// ---- flash attention: r5 shape (4 waves, 32 q/wave) + key-split x2 ----
// Q,K: [BH][N][D] bf16 (Q pre-scaled by 0.125*log2e); V^T: [BH][D][N]
// writes UNNORMALIZED partials: Opart bf16 [2][M][C], Lpart f32 [2][M][HH]
__global__ __launch_bounds__(256) void k_attn(const u16* __restrict__ Qb,
                                              const u16* __restrict__ Kb,
                                              const u16* __restrict__ VbT,
                                              u16* __restrict__ Opart,
                                              float* __restrict__ Lpart) {
    __shared__ __align__(16) u16 Ks[64][64];      // swizzled, 8KB
    __shared__ __align__(16) u16 Vs[64][64];      // 8KB
    __shared__ __align__(16) u16 Ps[4][32][64];   // per-wave 32q P^T, 16KB

    int t = threadIdx.x, wave = t >> 6, lane = t & 63;
    int quad = lane >> 4, l16 = lane & 15;
    int bh = blockIdx.y, sp = blockIdx.z;
    int q0 = blockIdx.x * 128 + wave * 32;        // this wave's 32 q
    const size_t kbase = (size_t)bh * NN * DD;
    const size_t vbase = (size_t)bh * DD * NN;

    bf16x8 qf[2][2];
#pragma unroll
    for (int qj = 0; qj < 2; qj++) {
        int qrow = q0 + qj * 16 + l16;
        qf[qj][0] = *(const bf16x8*)&Qb[kbase + (size_t)qrow * DD + quad * 8];
        qf[qj][1] = *(const bf16x8*)&Qb[kbase + (size_t)qrow * DD + 32 + quad * 8];
    }

    bf16x8 ones;
#pragma unroll
    for (int j = 0; j < 8; j++) ones[j] = (short)0x3F80;   // bf16 1.0

    f32x4 o[4][2];    // [dt][qj]: O^T rows d = dt*16+quad*4+r, col q = l16
    f32x4 accl[2];    // [qj]: all entries = l[q=l16]
#pragma unroll
    for (int i = 0; i < 4; i++)
#pragma unroll
        for (int j = 0; j < 2; j++) o[i][j] = f32x4{0.f, 0.f, 0.f, 0.f};
    accl[0] = f32x4{0.f, 0.f, 0.f, 0.f};
    accl[1] = f32x4{0.f, 0.f, 0.f, 0.f};

    int stgrp  = lane & 7;
    int stsrc  = (stgrp ^ (lane >> 3)) * 8;
    int strow0 = wave * 16 + (lane >> 3);         // + ii*8, ii=0..1
    int cf0 = (quad ^ (l16 & 7)) * 8;
    int cf1 = ((4 + quad) ^ (l16 & 7)) * 8;
    int psw = (quad & 1) * 4;

    for (int c = sp * 16; c < sp * 16 + 16; c++) {
        __syncthreads();
#pragma unroll
        for (int ii = 0; ii < 2; ii++) {
            int row = strow0 + ii * 8;
            ld_lds16(&Kb[kbase + (size_t)(c * 64 + row) * DD + stsrc], &Ks[row][stgrp * 8]);
            ld_lds16(&VbT[vbase + (size_t)row * NN + c * 64 + stsrc], &Vs[row][stgrp * 8]);
        }
        __syncthreads();

        // K-frags hoisted once, reused across 2 qj
        bf16x8 kf[4][2];
#pragma unroll
        for (int kt = 0; kt < 4; kt++) {
            kf[kt][0] = *(const bf16x8*)&Ks[kt * 16 + l16][cf0];
            kf[kt][1] = *(const bf16x8*)&Ks[kt * 16 + l16][cf1];
        }

#pragma unroll
        for (int qj = 0; qj < 2; qj++) {
            f32x4 s[4];
#pragma unroll
            for (int kt = 0; kt < 4; kt++) {
                f32x4 z = f32x4{0.f, 0.f, 0.f, 0.f};
                z = __builtin_amdgcn_mfma_f32_16x16x32_bf16(kf[kt][0], qf[qj][0], z, 0, 0, 0);
                z = __builtin_amdgcn_mfma_f32_16x16x32_bf16(kf[kt][1], qf[qj][1], z, 0, 0, 0);
                s[kt] = z;   // rows k = kt*16+quad*4+r, col q = l16
            }
#pragma unroll
            for (int kt = 0; kt < 4; kt++) {
                bfr4 pk;
#pragma unroll
                for (int r = 0; r < 4; r++) pk[r] = (__bf16)EXP2(s[kt][r]);
                int og = 2 * kt + (quad >> 1);
                *(bfr4*)&Ps[wave][qj * 16 + l16][(og ^ (l16 & 7)) * 8 + psw] = pk;
            }
        }
        // wave-local DS write->read ordering
        __asm__ volatile("s_waitcnt lgkmcnt(0)" ::: "memory");

        bf16x8 pb[2][2];
#pragma unroll
        for (int qj = 0; qj < 2; qj++) {
            pb[qj][0] = *(const bf16x8*)&Ps[wave][qj * 16 + l16][cf0];
            pb[qj][1] = *(const bf16x8*)&Ps[wave][qj * 16 + l16][cf1];
            accl[qj] = __builtin_amdgcn_mfma_f32_16x16x32_bf16(ones, pb[qj][0], accl[qj], 0, 0, 0);
            accl[qj] = __builtin_amdgcn_mfma_f32_16x16x32_bf16(ones, pb[qj][1], accl[qj], 0, 0, 0);
        }
#pragma unroll
        for (int dt = 0; dt < 4; dt++) {
            bf16x8 vf0 = *(const bf16x8*)&Vs[dt * 16 + l16][cf0];
            bf16x8 vf1 = *(const bf16x8*)&Vs[dt * 16 + l16][cf1];
#pragma unroll
            for (int qj = 0; qj < 2; qj++) {
                o[dt][qj] = __builtin_amdgcn_mfma_f32_16x16x32_bf16(vf0, pb[qj][0], o[dt][qj], 0, 0, 0);
                o[dt][qj] = __builtin_amdgcn_mfma_f32_16x16x32_bf16(vf1, pb[qj][1], o[dt][qj], 0, 0, 0);
            }
        }
    }

    // epilogue: write unnormalized bf16 partials + f32 l-partials
    int b = bh >> 4, h = bh & 15;
#pragma unroll
    for (int qj = 0; qj < 2; qj++) {
        int grow = b * NN + q0 + qj * 16 + l16;
        size_t orow = ((size_t)sp * MM + grow) * CC;
#pragma unroll
        for (int dt = 0; dt < 4; dt++) {
            u16x4 hv;
#pragma unroll
            for (int r = 0; r < 4; r++) hv[r] = f2bf(o[dt][qj][r]);
            *(u16x4*)&Opart[orow + h * DD + dt * 16 + quad * 4] = hv;
        }
        if (quad == 0)
            Lpart[((size_t)sp * MM + grow) * HH + h] = accl[qj][0];
    }
}

// ---- combine key-split partials, normalize, write bf16 Ob [M][C] ----
__global__ __launch_bounds__(256) void k_reduce(const u16* __restrict__ Op,
                                                const float* __restrict__ Lp,
                                                u16* __restrict__ Ob) {
    size_t i = ((size_t)blockIdx.x * 256 + threadIdx.x) * 8;
    int m = (int)(i >> 10);          // / CC
    int c = (int)(i & 1023);
    int h = c >> 6;
    float l = Lp[(size_t)m * HH + h] + Lp[(size_t)(MM + m) * HH + h];
    float inv = 1.f / l;
    u16x8 p0 = *(const u16x8*)&Op[i];
    u16x8 p1 = *(const u16x8*)&Op[(size_t)MM * CC + i];
    u16x8 o;
#pragma unroll
    for (int j = 0; j < 8; j++) o[j] = f2bf((bf2f(p0[j]) + bf2f(p1[j])) * inv);
    *(u16x8*)&Ob[i] = o;
}

extern "C" void kernel_launch(void* const* d_in, const int* in_sizes, int n_in,
                              void* d_out, int out_size, void* d_ws, size_t ws_size,
                              hipStream_t stream) {
    const float* x      = (const float*)d_in[0];
    const float* w_qkv  = (const float*)d_in[1];
    const float* w_proj = (const float*)d_in[2];
    const float* b_proj = (const float*)d_in[3];
    float* out = (float*)d_out;

    u16* p = (u16*)d_ws;
    u16* Xb = p; p += (size_t)MM * CC;
    u16* Wq = p; p += (size_t)NQKV * CC;
    u16* Wp = p; p += (size_t)CC * CC;
    u16* Qb = p; p += (size_t)MM * CC;
    u16* Kb = p; p += (size_t)MM * CC;
    u16* Vb = p; p += (size_t)MM * CC;           // V^T [BH][D][N]
    u16* Ob = p; p += (size_t)MM * CC;
    u16* Opart = p; p += (size_t)2 * MM * CC;    // bf16 partials [2][M][C]
    float* Lpart = (float*)p;                    // f32 [2][M][HH]

    k_tobf<<<(MM * CC) / (256 * 8), 256, 0, stream>>>(x, Xb, MM * CC);
    k_tcast<<<dim3(NQKV / 32, CC / 32), 256, 0, stream>>>(w_qkv, Wq, CC, NQKV);
    k_tcast<<<dim3(CC / 32, CC / 32), 256, 0, stream>>>(w_proj, Wp, CC, CC);
    k_gemm<0><<<dim3(NQKV / 128, MM / 128), 256, 0, stream>>>(
        Xb, Wq, Qb, Kb, Vb, nullptr, nullptr);
    k_attn<<<dim3(NN / 128, BB * HH, 2), 256, 0, stream>>>(Qb, Kb, Vb, Opart, Lpart);
    k_reduce<<<(MM * CC) / (256 * 8), 256, 0, stream>>>(Opart, Lpart, Ob);
    k_gemm<1><<<dim3(CC / 128, MM / 128), 256, 0, stream>>>(
        Ob, Wp, nullptr, nullptr, nullptr, b_proj, out);
}

// Round 10
// 207.404 us; speedup vs baseline: 1.0765x; 1.0070x over previous
//
#include <hip/hip_runtime.h>

typedef unsigned short u16;
typedef float f32x4 __attribute__((ext_vector_type(4)));
typedef short bf16x8 __attribute__((ext_vector_type(8)));
typedef u16 u16x4 __attribute__((ext_vector_type(4)));
typedef u16 u16x8 __attribute__((ext_vector_type(8)));
typedef __bf16 bfr4 __attribute__((ext_vector_type(4)));

// ---- constants ----
#define BB 2
#define NN 2048
#define CC 1024
#define HH 16
#define DD 64
#define MM (BB * NN)          // 4096 rows
#define NQKV (3 * CC)         // 3072
#define QSCALE 0.18033688011112042f   // 0.125 * log2(e): scores in log2 domain

#if __has_builtin(__builtin_amdgcn_exp2f)
#define EXP2(x) __builtin_amdgcn_exp2f(x)
#else
#define EXP2(x) exp2f(x)
#endif

__device__ __forceinline__ u16 f2bf(float f) {
    unsigned u = __float_as_uint(f);
    u += 0x7FFFu + ((u >> 16) & 1u);   // round-to-nearest-even
    return (u16)(u >> 16);
}
__device__ __forceinline__ float bf2f(u16 b) {
    return __uint_as_float(((unsigned)b) << 16);
}

// async global->LDS, 16B per lane. LDS dst must be wave-uniform base + lane*16.
__device__ __forceinline__ void ld_lds16(const u16* g, u16* l) {
    __builtin_amdgcn_global_load_lds(
        (const __attribute__((address_space(1))) unsigned int*)g,
        (__attribute__((address_space(3))) unsigned int*)l, 16, 0, 0);
}

// ---- fp32 -> bf16 cast (x) ----
__global__ __launch_bounds__(256) void k_tobf(const float* __restrict__ in,
                                              u16* __restrict__ out, int n) {
    int i = (blockIdx.x * 256 + threadIdx.x) * 8;
    if (i >= n) return;
    float4 a = *(const float4*)(in + i);
    float4 b = *(const float4*)(in + i + 4);
    u16x8 o;
    o[0] = f2bf(a.x); o[1] = f2bf(a.y); o[2] = f2bf(a.z); o[3] = f2bf(a.w);
    o[4] = f2bf(b.x); o[5] = f2bf(b.y); o[6] = f2bf(b.z); o[7] = f2bf(b.w);
    *(u16x8*)(out + i) = o;
}

// ---- transpose-cast [K][Nn] fp32 -> [Nn][K] bf16 (weights) ----
__global__ __launch_bounds__(256) void k_tcast(const float* __restrict__ in,
                                               u16* __restrict__ out,
                                               int K, int Nn) {
    __shared__ float tile[32][33];
    int t = threadIdx.x, tx = t & 31, ty = t >> 5;
    int n0 = blockIdx.x * 32, k0 = blockIdx.y * 32;
#pragma unroll
    for (int r = 0; r < 32; r += 8)
        tile[ty + r][tx] = in[(size_t)(k0 + ty + r) * Nn + n0 + tx];
    __syncthreads();
#pragma unroll
    for (int r = 0; r < 32; r += 8)
        out[(size_t)(n0 + ty + r) * K + k0 + tx] = f2bf(tile[tx][ty + r]);
}

// ---- plain bf16 GEMM C = A @ B^T, K=1024, BK=32 (round-5 config) ----
template <int MODE>
__global__ __launch_bounds__(256) void k_gemm(
    const u16* __restrict__ A, const u16* __restrict__ B,
    u16* __restrict__ Qb, u16* __restrict__ Kb, u16* __restrict__ Vb,
    const float* __restrict__ bias, float* __restrict__ Cout) {
    const int Kd = 1024;
    __shared__ __align__(16) u16 Ah[128][32];
    __shared__ __align__(16) u16 Bh[128][32];

    int t = threadIdx.x;
    int wave = t >> 6, lane = t & 63;
    int quad = lane >> 4, l16 = lane & 15;
    int wm = (wave >> 1) * 64, wn = (wave & 1) * 64;
    int m0 = blockIdx.y * 128, n0 = blockIdx.x * 128;

    int strow0 = wave * 16 + (lane >> 2);              // + ii*64
    int stdst  = (lane & 3) * 8;                       // lds col (u16)
    int stsrc  = ((lane & 3) ^ ((lane >> 3) & 3)) * 8; // global col (u16)
    int cfrag = (quad ^ ((l16 >> 1) & 3)) * 8;

    f32x4 acc[4][4];
#pragma unroll
    for (int i = 0; i < 4; i++)
#pragma unroll
        for (int j = 0; j < 4; j++) acc[i][j] = f32x4{0.f, 0.f, 0.f, 0.f};

    for (int k0 = 0; k0 < Kd; k0 += 32) {
        __syncthreads();
#pragma unroll
        for (int ii = 0; ii < 2; ii++) {
            int row = strow0 + ii * 64;
            ld_lds16(A + (size_t)(m0 + row) * Kd + k0 + stsrc, &Ah[row][stdst]);
            ld_lds16(B + (size_t)(n0 + row) * Kd + k0 + stsrc, &Bh[row][stdst]);
        }
        __syncthreads();

        bf16x8 af[4], bf[4];
#pragma unroll
        for (int i = 0; i < 4; i++) {
            af[i] = *(const bf16x8*)&Ah[wm + i * 16 + l16][cfrag];
            bf[i] = *(const bf16x8*)&Bh[wn + i * 16 + l16][cfrag];
        }
#pragma unroll
        for (int mi = 0; mi < 4; mi++)
#pragma unroll
            for (int ni = 0; ni < 4; ni++)
                acc[mi][ni] = __builtin_amdgcn_mfma_f32_16x16x32_bf16(
                    af[mi], bf[ni], acc[mi][ni], 0, 0, 0);
    }

#pragma unroll
    for (int mi = 0; mi < 4; mi++)
#pragma unroll
        for (int ni = 0; ni < 4; ni++)
#pragma unroll
            for (int r = 0; r < 4; r++) {
                int grow = m0 + wm + mi * 16 + quad * 4 + r;
                int gcol = n0 + wn + ni * 16 + l16;
                float v = acc[mi][ni][r];
                if (MODE == 0) {
                    int three = gcol >> 10, rem = gcol & 1023;
                    int h = rem >> 6, d = rem & 63;
                    int bb = grow >> 11, nn = grow & 2047;
                    if (three == 0) {
                        Qb[((size_t)(bb * HH + h) * NN + nn) * DD + d] = f2bf(v * QSCALE);
                    } else if (three == 1) {
                        Kb[((size_t)(bb * HH + h) * NN + nn) * DD + d] = f2bf(v);
                    } else {
                        Vb[((size_t)(bb * HH + h) * DD + d) * NN + nn] = f2bf(v);
                    }
                } else {
                    Cout[(size_t)grow * CC + gcol] = v + bias[gcol];
                }
            }
}

// ---- flash attention: r9 shape + single-barrier double-buffered staging ----
// Q,K: [BH][N][D] bf16 (Q pre-scaled by 0.125*log2e); V^T: [BH][D][N]
// writes UNNORMALIZED partials: Opart bf16 [2][M][C], Lpart f32 [2][M][HH]
__global__ __launch_bounds__(256) void k_attn(const u16* __restrict__ Qb,
                                              const u16* __restrict__ Kb,
                                              const u16* __restrict__ VbT,
                                              u16* __restrict__ Opart,
                                              float* __restrict__ Lpart) {
    __shared__ __align__(16) u16 Ks[2][64][64];   // dbuf, swizzled, 16KB
    __shared__ __align__(16) u16 Vs[2][64][64];   // 16KB
    __shared__ __align__(16) u16 Ps[4][32][64];   // per-wave 32q P^T, 16KB

    int t = threadIdx.x, wave = t >> 6, lane = t & 63;
    int quad = lane >> 4, l16 = lane & 15;
    int bh = blockIdx.y, sp = blockIdx.z;
    int q0 = blockIdx.x * 128 + wave * 32;        // this wave's 32 q
    const size_t kbase = (size_t)bh * NN * DD;
    const size_t vbase = (size_t)bh * DD * NN;

    bf16x8 qf[2][2];
#pragma unroll
    for (int qj = 0; qj < 2; qj++) {
        int qrow = q0 + qj * 16 + l16;
        qf[qj][0] = *(const bf16x8*)&Qb[kbase + (size_t)qrow * DD + quad * 8];
        qf[qj][1] = *(const bf16x8*)&Qb[kbase + (size_t)qrow * DD + 32 + quad * 8];
    }

    bf16x8 ones;
#pragma unroll
    for (int j = 0; j < 8; j++) ones[j] = (short)0x3F80;   // bf16 1.0

    f32x4 o[4][2];    // [dt][qj]: O^T rows d = dt*16+quad*4+r, col q = l16
    f32x4 accl[2];    // [qj]: all entries = l[q=l16]
#pragma unroll
    for (int i = 0; i < 4; i++)
#pragma unroll
        for (int j = 0; j < 2; j++) o[i][j] = f32x4{0.f, 0.f, 0.f, 0.f};
    accl[0] = f32x4{0.f, 0.f, 0.f, 0.f};
    accl[1] = f32x4{0.f, 0.f, 0.f, 0.f};

    int stgrp  = lane & 7;
    int stsrc  = (stgrp ^ (lane >> 3)) * 8;
    int strow0 = wave * 16 + (lane >> 3);         // + ii*8, ii=0..1
    int cf0 = (quad ^ (l16 & 7)) * 8;
    int cf1 = ((4 + quad) ^ (l16 & 7)) * 8;
    int psw = (quad & 1) * 4;

    const int c0 = sp * 16;

    // prologue: stage chunk c0 into buffer 0
#pragma unroll
    for (int ii = 0; ii < 2; ii++) {
        int row = strow0 + ii * 8;
        ld_lds16(&Kb[kbase + (size_t)(c0 * 64 + row) * DD + stsrc], &Ks[0][row][stgrp * 8]);
        ld_lds16(&VbT[vbase + (size_t)row * NN + c0 * 64 + stsrc], &Vs[0][row][stgrp * 8]);
    }

    for (int i = 0; i < 16; i++) {
        // barrier drains each wave's outstanding global_load_lds (vmcnt(0)):
        // the prefetch issued last iteration has had a full compute phase to fly.
        __syncthreads();
        if (i < 15) {
            int c = c0 + i + 1, nb = (i + 1) & 1;
#pragma unroll
            for (int ii = 0; ii < 2; ii++) {
                int row = strow0 + ii * 8;
                ld_lds16(&Kb[kbase + (size_t)(c * 64 + row) * DD + stsrc], &Ks[nb][row][stgrp * 8]);
                ld_lds16(&VbT[vbase + (size_t)row * NN + c * 64 + stsrc], &Vs[nb][row][stgrp * 8]);
            }
        }
        const int bi = i & 1;

        // K-frags hoisted once, reused across 2 qj
        bf16x8 kf[4][2];
#pragma unroll
        for (int kt = 0; kt < 4; kt++) {
            kf[kt][0] = *(const bf16x8*)&Ks[bi][kt * 16 + l16][cf0];
            kf[kt][1] = *(const bf16x8*)&Ks[bi][kt * 16 + l16][cf1];
        }

#pragma unroll
        for (int qj = 0; qj < 2; qj++) {
            f32x4 s[4];
#pragma unroll
            for (int kt = 0; kt < 4; kt++) {
                f32x4 z = f32x4{0.f, 0.f, 0.f, 0.f};
                z = __builtin_amdgcn_mfma_f32_16x16x32_bf16(kf[kt][0], qf[qj][0], z, 0, 0, 0);
                z = __builtin_amdgcn_mfma_f32_16x16x32_bf16(kf[kt][1], qf[qj][1], z, 0, 0, 0);
                s[kt] = z;   // rows k = kt*16+quad*4+r, col q = l16
            }
#pragma unroll
            for (int kt = 0; kt < 4; kt++) {
                bfr4 pk;
#pragma unroll
                for (int r = 0; r < 4; r++) pk[r] = (__bf16)EXP2(s[kt][r]);
                int og = 2 * kt + (quad >> 1);
                *(bfr4*)&Ps[wave][qj * 16 + l16][(og ^ (l16 & 7)) * 8 + psw] = pk;
            }
        }
        // wave-local DS write->read ordering
        __asm__ volatile("s_waitcnt lgkmcnt(0)" ::: "memory");

        bf16x8 pb[2][2];
#pragma unroll
        for (int qj = 0; qj < 2; qj++) {
            pb[qj][0] = *(const bf16x8*)&Ps[wave][qj * 16 + l16][cf0];
            pb[qj][1] = *(const bf16x8*)&Ps[wave][qj * 16 + l16][cf1];
            accl[qj] = __builtin_amdgcn_mfma_f32_16x16x32_bf16(ones, pb[qj][0], accl[qj], 0, 0, 0);
            accl[qj] = __builtin_amdgcn_mfma_f32_16x16x32_bf16(ones, pb[qj][1], accl[qj], 0, 0, 0);
        }
#pragma unroll
        for (int dt = 0; dt < 4; dt++) {
            bf16x8 vf0 = *(const bf16x8*)&Vs[bi][dt * 16 + l16][cf0];
            bf16x8 vf1 = *(const bf16x8*)&Vs[bi][dt * 16 + l16][cf1];
#pragma unroll
            for (int qj = 0; qj < 2; qj++) {
                o[dt][qj] = __builtin_amdgcn_mfma_f32_16x16x32_bf16(vf0, pb[qj][0], o[dt][qj], 0, 0, 0);
                o[dt][qj] = __builtin_amdgcn_mfma_f32_16x16x32_bf16(vf1, pb[qj][1], o[dt][qj], 0, 0, 0);
            }
        }
    }

    // epilogue: write unnormalized bf16 partials + f32 l-partials
    int b = bh >> 4, h = bh & 15;
#pragma unroll
    for (int qj = 0; qj < 2; qj++) {
        int grow = b * NN + q0 + qj * 16 + l16;
        size_t orow = ((size_t)sp * MM + grow) * CC;
#pragma unroll
        for (int dt = 0; dt < 4; dt++) {
            u16x4 hv;
#pragma unroll
            for (int r = 0; r < 4; r++) hv[r] = f2bf(o[dt][qj][r]);
            *(u16x4*)&Opart[orow + h * DD + dt * 16 + quad * 4] = hv;
        }
        if (quad == 0)
            Lpart[((size_t)sp * MM + grow) * HH + h] = accl[qj][0];
    }
}

// ---- combine key-split partials, normalize, write bf16 Ob [M][C] ----
__global__ __launch_bounds__(256) void k_reduce(const u16* __restrict__ Op,
                                                const float* __restrict__ Lp,
                                                u16* __restrict__ Ob) {
    size_t i = ((size_t)blockIdx.x * 256 + threadIdx.x) * 8;
    int m = (int)(i >> 10);          // / CC
    int c = (int)(i & 1023);
    int h = c >> 6;
    float l = Lp[(size_t)m * HH + h] + Lp[(size_t)(MM + m) * HH + h];
    float inv = 1.f / l;
    u16x8 p0 = *(const u16x8*)&Op[i];
    u16x8 p1 = *(const u16x8*)&Op[(size_t)MM * CC + i];
    u16x8 o;
#pragma unroll
    for (int j = 0; j < 8; j++) o[j] = f2bf((bf2f(p0[j]) + bf2f(p1[j])) * inv);
    *(u16x8*)&Ob[i] = o;
}

extern "C" void kernel_launch(void* const* d_in, const int* in_sizes, int n_in,
                              void* d_out, int out_size, void* d_ws, size_t ws_size,
                              hipStream_t stream) {
    const float* x      = (const float*)d_in[0];
    const float* w_qkv  = (const float*)d_in[1];
    const float* w_proj = (const float*)d_in[2];
    const float* b_proj = (const float*)d_in[3];
    float* out = (float*)d_out;

    u16* p = (u16*)d_ws;
    u16* Xb = p; p += (size_t)MM * CC;
    u16* Wq = p; p += (size_t)NQKV * CC;
    u16* Wp = p; p += (size_t)CC * CC;
    u16* Qb = p; p += (size_t)MM * CC;
    u16* Kb = p; p += (size_t)MM * CC;
    u16* Vb = p; p += (size_t)MM * CC;           // V^T [BH][D][N]
    u16* Ob = p; p += (size_t)MM * CC;
    u16* Opart = p; p += (size_t)2 * MM * CC;    // bf16 partials [2][M][C]
    float* Lpart = (float*)p;                    // f32 [2][M][HH]

    k_tobf<<<(MM * CC) / (256 * 8), 256, 0, stream>>>(x, Xb, MM * CC);
    k_tcast<<<dim3(NQKV / 32, CC / 32), 256, 0, stream>>>(w_qkv, Wq, CC, NQKV);
    k_tcast<<<dim3(CC / 32, CC / 32), 256, 0, stream>>>(w_proj, Wp, CC, CC);
    k_gemm<0><<<dim3(NQKV / 128, MM / 128), 256, 0, stream>>>(
        Xb, Wq, Qb, Kb, Vb, nullptr, nullptr);
    k_attn<<<dim3(NN / 128, BB * HH, 2), 256, 0, stream>>>(Qb, Kb, Vb, Opart, Lpart);
    k_reduce<<<(MM * CC) / (256 * 8), 256, 0, stream>>>(Opart, Lpart, Ob);
    k_gemm<1><<<dim3(CC / 128, MM / 128), 256, 0, stream>>>(
        Ob, Wp, nullptr, nullptr, nullptr, b_proj, out);
}